// Round 17
// baseline (157.256 us; speedup 1.0000x reference)
//
#include <hip/hip_runtime.h>

typedef __bf16 bf16x8 __attribute__((ext_vector_type(8)));
typedef __bf16 bf16x4 __attribute__((ext_vector_type(4)));
typedef __bf16 bf16x2 __attribute__((ext_vector_type(2)));
typedef float f32x4 __attribute__((ext_vector_type(4)));
typedef float f32x16 __attribute__((ext_vector_type(16)));

#define MFMA16(a, b, c) __builtin_amdgcn_mfma_f32_16x16x32_bf16(a, b, c, 0, 0, 0)
#define MFMA32(a, b, c) __builtin_amdgcn_mfma_f32_32x32x16_bf16(a, b, c, 0, 0, 0)

// ATT_SCALE * log2(e): Q projection pre-scaled so softmax uses exp2 directly.
static constexpr float QSCALE = 0.15811388300841897f * 1.4426950408889634f;

// raw v_exp_f32 (exp2f without OCML denormal-range wrapper; scores are bounded)
__device__ __forceinline__ float fexp2(float x) { return __builtin_amdgcn_exp2f(x); }

// direct global->LDS DMA, 16B per lane. LDS dst must be wave-uniform base.
__device__ __forceinline__ void gload16(const __bf16* g, __bf16* l) {
  __builtin_amdgcn_global_load_lds((const __attribute__((address_space(1))) void*)g,
                                   (__attribute__((address_space(3))) void*)l, 16, 0, 0);
}

__device__ __forceinline__ bf16x8 zero8() {
  bf16x8 z;
#pragma unroll
  for (int j = 0; j < 8; ++j) z[j] = (__bf16)0.0f;
  return z;
}

__device__ __forceinline__ bf16x8 ones8() {
  bf16x8 z;
#pragma unroll
  for (int j = 0; j < 8; ++j) z[j] = (__bf16)1.0f;
  return z;
}

__device__ __forceinline__ float gelu_exact(float x) {
  return 0.5f * x * (1.0f + erff(x * 0.70710678118654752f));
}

// LN-on-load: 8 contiguous f32 from h row -> normalized bf16x8.
__device__ __forceinline__ bf16x8 ln8(const float* hrow, int c, float mu, float rstd,
                                      const float* g, const float* b) {
  float4 x = *(const float4*)(hrow + c);
  float4 y = *(const float4*)(hrow + c + 4);
  float4 g0 = *(const float4*)(g + c);
  float4 g1 = *(const float4*)(g + c + 4);
  float4 b0 = *(const float4*)(b + c);
  float4 b1 = *(const float4*)(b + c + 4);
  bf16x8 o;
  o[0] = (__bf16)((x.x - mu) * rstd * g0.x + b0.x);
  o[1] = (__bf16)((x.y - mu) * rstd * g0.y + b0.y);
  o[2] = (__bf16)((x.z - mu) * rstd * g0.z + b0.z);
  o[3] = (__bf16)((x.w - mu) * rstd * g0.w + b0.w);
  o[4] = (__bf16)((y.x - mu) * rstd * g1.x + b1.x);
  o[5] = (__bf16)((y.y - mu) * rstd * g1.y + b1.y);
  o[6] = (__bf16)((y.z - mu) * rstd * g1.z + b1.z);
  o[7] = (__bf16)((y.w - mu) * rstd * g1.w + b1.w);
  return o;
}

__device__ __forceinline__ void rowstat(const float* rs, int row, float& mu, float& rstd) {
  float2 st = *(const float2*)&rs[row * 2];
  mu = st.x * (1.f / 320.f);
  rstd = rsqrtf(st.y * (1.f / 320.f) - mu * mu + 1e-5f);
}

// ---------------- prep: weight convert + GN stats + zero LN-stats (merged) ----
struct WDesc { const float* src; __bf16* dst; int K; int N; int ldn; int noff; };
struct WTable { WDesc w[12]; };

__global__ __launch_bounds__(256) void prep_kernel(WTable tab,
                                                   const float* __restrict__ X,
                                                   float* __restrict__ part,
                                                   float* __restrict__ rsall) {
  __shared__ float rs[4], rs2[4];
  int id = blockIdx.x;
  if (id < 4800) {
    WDesc d = tab.w[id / 400];
    int total = (d.K >> 3) * d.N;
    int idx = (id % 400) * 256 + threadIdx.x;
    if (idx >= total) return;
    int kb = idx / d.N, n = idx - kb * d.N;
    bf16x8 o;
#pragma unroll
    for (int j = 0; j < 8; ++j) o[j] = (__bf16)d.src[(size_t)(kb * 8 + j) * d.N + n];
    *(bf16x8*)&d.dst[((size_t)kb * d.ldn + d.noff + n) * 8] = o;
  } else if (id < 5056) {
    int gb = id - 4800;  // 0..255
    int g = gb >> 3, cid = gb & 7;
    const float* base = X + (size_t)g * 40960 + (size_t)cid * 5120;
    int t = threadIdx.x;
    float s = 0.f, s2 = 0.f;
#pragma unroll
    for (int i = t; i < 1280; i += 256) {
      float4 v = ((const float4*)base)[i];
      s += v.x + v.y + v.z + v.w;
      s2 += v.x * v.x + v.y * v.y + v.z * v.z + v.w * v.w;
    }
#pragma unroll
    for (int off = 1; off < 64; off <<= 1) { s += __shfl_xor(s, off); s2 += __shfl_xor(s2, off); }
    int wid = t >> 6, lane = t & 63;
    if (lane == 0) { rs[wid] = s; rs2[wid] = s2; }
    __syncthreads();
    if (t == 0) {
      part[gb * 2] = rs[0] + rs[1] + rs[2] + rs[3];
      part[gb * 2 + 1] = rs2[0] + rs2[1] + rs2[2] + rs2[3];
    }
  } else {
    // zero the 3 LN-stats buffers (24576 floats)
    int zb = id - 5056;  // 0..11
    float4 z = {0.f, 0.f, 0.f, 0.f};
    float* dst = rsall + ((size_t)zb * 256 + threadIdx.x) * 8;
    *(float4*)dst = z;
    *(float4*)(dst + 4) = z;
  }
}

__global__ __launch_bounds__(256) void gn_apply(const float* __restrict__ X,
                                                const float* __restrict__ part,
                                                const float* __restrict__ gg,
                                                const float* __restrict__ gb,
                                                __bf16* __restrict__ Y) {
  int i0 = (blockIdx.x * 256 + threadIdx.x) * 8;
  int c = i0 >> 12, px = i0 & 4095;
  int g = c / 10;
  float s = 0.f, s2 = 0.f;
#pragma unroll
  for (int j = 0; j < 8; ++j) { s += part[(g * 8 + j) * 2]; s2 += part[(g * 8 + j) * 2 + 1]; }
  float mu = s * (1.f / 40960.f);
  float rstd = rsqrtf(s2 * (1.f / 40960.f) - mu * mu + 1e-6f);
  float ga = gg[c] * rstd, bb = gb[c] - mu * ga;
  float4 a = *(const float4*)&X[i0];
  float4 b = *(const float4*)&X[i0 + 4];
  Y[(size_t)(px + 0) * 320 + c] = (__bf16)(a.x * ga + bb);
  Y[(size_t)(px + 1) * 320 + c] = (__bf16)(a.y * ga + bb);
  Y[(size_t)(px + 2) * 320 + c] = (__bf16)(a.z * ga + bb);
  Y[(size_t)(px + 3) * 320 + c] = (__bf16)(a.w * ga + bb);
  Y[(size_t)(px + 4) * 320 + c] = (__bf16)(b.x * ga + bb);
  Y[(size_t)(px + 5) * 320 + c] = (__bf16)(b.y * ga + bb);
  Y[(size_t)(px + 6) * 320 + c] = (__bf16)(b.z * ga + bb);
  Y[(size_t)(px + 7) * 320 + c] = (__bf16)(b.w * ga + bb);
}

// ---------------- 32x64 bf16 GEMM, BK=64, 1D grid + XCD chunk swizzle ---------
// OM: 0=f32 out, 1=bf16 out, 2=f32+bf16, 3=transposed f32, 4=head-blocked pad48.
// ST: emit per-row (sum,sumsq) atomics for downstream LN. LNA: A = LN(Hsrc) on
// the fly (reg-staged) instead of gload16 from A.
template <int OM, bool HB, bool HR, bool QS, bool AH, bool ST, bool LNA>
__global__ __launch_bounds__(256) void gemm32(const __bf16* __restrict__ A,
                                              const __bf16* __restrict__ Bt,
                                              const float* __restrict__ bias,
                                              const float* __restrict__ res,
                                              void* __restrict__ Cout,
                                              void* __restrict__ Cout2,
                                              int M, int N, int K,
                                              float* __restrict__ rso,
                                              const float* __restrict__ Hsrc,
                                              const float* __restrict__ rsi,
                                              const float* __restrict__ lng,
                                              const float* __restrict__ lnb) {
  __shared__ __align__(16) __bf16 sA[2][2048];
  __shared__ __align__(16) __bf16 sB[2][4096];
  int t = threadIdx.x, lane = t & 63, wid = t >> 6;
  int wr = wid >> 1, wc = wid & 1, kb4 = lane >> 4, l15 = lane & 15;
  int id = blockIdx.x;
  int id2 = (id & 7) * 80 + (id >> 3);
  int bx = id2 / 5, by = id2 - bx * 5;
  int m0 = bx * 32, n0 = by * 64;
  const size_t N8 = (size_t)N * 8;
  f32x4 acc[2] = {};
  int r0 = t >> 3, c0 = (t & 7) ^ (r0 & 7);

  float muA = 0.f, rstdA = 0.f;
  if (LNA) rowstat(rsi, m0 + r0, muA, rstdA);

  auto stage = [&](int buf, int k0) {
    if (LNA) {
      const float* hrow = Hsrc + (size_t)(m0 + r0) * 320;
      *(bf16x8*)&sA[buf][(size_t)t * 8] = ln8(hrow, k0 + c0 * 8, muA, rstdA, lng, lnb);
    } else {
      const __bf16* ga0;
      if (AH) {
        int kk = k0 + c0 * 8;
        int hh = kk / 40, dh = kk - hh * 40;
        ga0 = &A[((size_t)hh * 4096 + m0 + r0) * 40 + dh];
      } else {
        ga0 = &A[(size_t)(m0 + r0) * K + k0 + c0 * 8];
      }
      gload16(ga0, &sA[buf][wid * 512]);
    }
    gload16(&Bt[((size_t)(k0 >> 3) + wid) * N8 + (size_t)(n0 + lane) * 8], &sB[buf][wid * 512]);
    gload16(&Bt[((size_t)(k0 >> 3) + wid + 4) * N8 + (size_t)(n0 + lane) * 8], &sB[buf][2048 + wid * 512]);
  };
  stage(0, 0);
  __syncthreads();
  int cur = 0;
  for (int k0 = 0; k0 < K; k0 += 64) {
    if (k0 + 64 < K) stage(cur ^ 1, k0 + 64);
#pragma unroll
    for (int kk = 0; kk < 2; ++kk) {
      int c8 = kb4 + kk * 4;
      int row = wr * 16 + l15;
      bf16x8 af = *(const bf16x8*)&sA[cur][row * 64 + ((c8 * 8) ^ ((row & 7) << 3))];
      bf16x8 bfr[2];
#pragma unroll
      for (int fn = 0; fn < 2; ++fn)
        bfr[fn] = *(const bf16x8*)&sB[cur][(c8 * 64 + wc * 32 + fn * 16 + l15) * 8];
#pragma unroll
      for (int fn = 0; fn < 2; ++fn) acc[fn] = MFMA16(af, bfr[fn], acc[fn]);
    }
    __syncthreads();
    cur ^= 1;
  }
#pragma unroll
  for (int r = 0; r < 4; ++r) {
    float sv = 0.f, sv2 = 0.f;
    int row = m0 + wr * 16 + kb4 * 4 + r;
#pragma unroll
    for (int fn = 0; fn < 2; ++fn) {
      int col = n0 + wc * 32 + fn * 16 + l15;
      float v = acc[fn][r];
      if (HB) v += bias[col];
      if (OM == 3) {
        if (HR) v += res[(size_t)col * M + row];
        ((float*)Cout)[(size_t)col * M + row] = v;
      } else if (OM == 4) {
        int hh = col / 40, dh = col - hh * 40;
        __bf16* qp = (__bf16*)Cout + ((size_t)hh * 4096 + row) * 48 + dh;
        *qp = (__bf16)(QS ? v * QSCALE : v);
        if (dh >= 32) qp[8] = (__bf16)0.f;
      } else {
        if (HR) v += res[(size_t)row * N + col];
        if (OM == 0) {
          ((float*)Cout)[(size_t)row * N + col] = v;
        } else if (OM == 1) {
          ((__bf16*)Cout)[(size_t)row * N + col] = (__bf16)(QS ? v * QSCALE : v);
        } else {
          ((float*)Cout)[(size_t)row * N + col] = v;
          ((__bf16*)Cout2)[(size_t)row * N + col] = (__bf16)v;
        }
      }
      if (ST) { sv += v; sv2 += v * v; }
    }
    if (ST) {
#pragma unroll
      for (int off = 1; off < 16; off <<= 1) {
        sv += __shfl_xor(sv, off);
        sv2 += __shfl_xor(sv2, off);
      }
      if (l15 == 0) {
        atomicAdd(&rso[row * 2], sv);
        atomicAdd(&rso[row * 2 + 1], sv2);
      }
    }
  }
}

// ---- K/V fragment-order scatter helpers (write side of register-direct attn) -
__device__ __forceinline__ void scatterK(__bf16* Kf, int NT, int hh, int row, int dh, float v) {
  int tile = row >> 6, kg = (row >> 5) & 1, k31 = row & 31;
  int s = dh >> 4, hi = (dh >> 3) & 1, j = dh & 7;
  size_t base = (((size_t)hh * NT + tile) * 2 + kg) * 3;
  Kf[(base + s) * 512 + (hi * 32 + k31) * 8 + j] = (__bf16)v;
  if (dh >= 32)  // zero-fill the d=40..47 slice (s=2, hi=1)
    Kf[(base + 2) * 512 + (32 + k31) * 8 + (dh & 7)] = (__bf16)0.f;
}
__device__ __forceinline__ void scatterV(__bf16* Vfl, __bf16* Vfh, int NT, int hh,
                                         int row, int dh, float v) {
  int tile = row >> 6, kg = (row >> 5) & 1, klo = row & 31;
  int m = (klo >> 4) & 1, hik = (klo >> 2) & 1;
  int jj = (klo & 3) | (((klo >> 3) & 1) << 2);
  size_t base = (((size_t)hh * NT + tile) * 2 + kg) * 2 + m;
  if (dh < 32) Vfl[base * 512 + (hik * 32 + dh) * 8 + jj] = (__bf16)v;
  else Vfh[base * 128 + (hik * 8 + (dh - 32)) * 8 + jj] = (__bf16)v;
}

// ---------------- merged QKV GEMM (blocks 0..959, LN-on-load A) + KV2 (960..979)
__global__ __launch_bounds__(256) void qkv_gemm(const float* __restrict__ Hsrc,
                                                const float* __restrict__ rsi,
                                                const float* __restrict__ lng,
                                                const float* __restrict__ lnb,
                                                const __bf16* __restrict__ Bt,
                                                __bf16* __restrict__ Qh,
                                                __bf16* __restrict__ Kf,
                                                __bf16* __restrict__ Vfl,
                                                __bf16* __restrict__ Vfh,
                                                const float* __restrict__ ctx,
                                                const __bf16* __restrict__ wKV2,
                                                __bf16* __restrict__ Kf2,
                                                __bf16* __restrict__ Vfl2,
                                                __bf16* __restrict__ Vfh2) {
  __shared__ __align__(16) char smem[32768];
  __bf16* sA = (__bf16*)smem;            // qkv: [2][4096]; kv2: [2][2048]
  __bf16* sB = (__bf16*)(smem + 16384);  // qkv: [2][4096]; kv2: [2][2048]
  int t = threadIdx.x, lane = t & 63, wid = t >> 6;
  int wr = wid >> 1, wc = wid & 1, kb4 = lane >> 4, l15 = lane & 15;

  if (blockIdx.x < 960) {
    int id = blockIdx.x;
    int id2 = (id & 7) * 120 + (id >> 3);
    int bx = id2 / 15, by = id2 - bx * 15;
    int m0 = bx * 64, n0 = by * 64;
    f32x4 acc[2][2] = {};
    int r0 = t >> 3, c0 = (t & 7) ^ (r0 & 7);
    float muA, rstdA, muB, rstdB;
    rowstat(rsi, m0 + r0, muA, rstdA);
    rowstat(rsi, m0 + 32 + r0, muB, rstdB);
    const float* hrowA = Hsrc + (size_t)(m0 + r0) * 320;
    const float* hrowB = Hsrc + (size_t)(m0 + 32 + r0) * 320;

    auto stage = [&](int buf, int k0) {
      int c = k0 + c0 * 8;
      *(bf16x8*)&sA[buf * 4096 + (size_t)t * 8] = ln8(hrowA, c, muA, rstdA, lng, lnb);
      *(bf16x8*)&sA[buf * 4096 + 2048 + (size_t)t * 8] = ln8(hrowB, c, muB, rstdB, lng, lnb);
      gload16(&Bt[((size_t)(k0 >> 3) + wid) * (960 * 8) + (size_t)(n0 + lane) * 8], &sB[buf * 4096 + wid * 512]);
      gload16(&Bt[((size_t)(k0 >> 3) + wid + 4) * (960 * 8) + (size_t)(n0 + lane) * 8], &sB[buf * 4096 + 2048 + wid * 512]);
    };
    stage(0, 0);
    __syncthreads();
    int cur = 0;
    for (int k0 = 0; k0 < 320; k0 += 64) {
      if (k0 + 64 < 320) stage(cur ^ 1, k0 + 64);
#pragma unroll
      for (int kk = 0; kk < 2; ++kk) {
        int c8 = kb4 + kk * 4;
        bf16x8 af[2], bfr[2];
#pragma unroll
        for (int fm = 0; fm < 2; ++fm) {
          int row = wr * 32 + fm * 16 + l15;
          af[fm] = *(const bf16x8*)&sA[cur * 4096 + row * 64 + ((c8 * 8) ^ ((row & 7) << 3))];
        }
#pragma unroll
        for (int fn = 0; fn < 2; ++fn)
          bfr[fn] = *(const bf16x8*)&sB[cur * 4096 + (c8 * 64 + wc * 32 + fn * 16 + l15) * 8];
#pragma unroll
        for (int fm = 0; fm < 2; ++fm)
#pragma unroll
          for (int fn = 0; fn < 2; ++fn) acc[fm][fn] = MFMA16(af[fm], bfr[fn], acc[fm][fn]);
      }
      __syncthreads();
      cur ^= 1;
    }
#pragma unroll
    for (int fm = 0; fm < 2; ++fm)
#pragma unroll
      for (int fn = 0; fn < 2; ++fn)
#pragma unroll
        for (int r = 0; r < 4; ++r) {
          int row = m0 + wr * 32 + fm * 16 + kb4 * 4 + r;
          int col = n0 + wc * 32 + fn * 16 + l15;
          float v = acc[fm][fn][r];
          if (col < 320) {
            int hh = col / 40, dh = col - hh * 40;
            __bf16* qp = &Qh[((size_t)hh * 4096 + row) * 48 + dh];
            *qp = (__bf16)(v * QSCALE);
            if (dh >= 32) qp[8] = (__bf16)0.f;
          } else if (col < 640) {
            int d = col - 320;
            int hh = d / 40, dh = d - hh * 40;
            scatterK(Kf, 64, hh, row, dh, v);
          } else {
            int d = col - 640;
            int hh = d / 40, dh = d - hh * 40;
            scatterV(Vfl, Vfh, 64, hh, row, dh, v);
          }
        }
  } else {
    // ---- cross K/V GEMM: 20 blocks (bx in 0..1, by in 0..9) ----
    int id2 = blockIdx.x - 960;
    int bx = id2 & 1, by = id2 >> 1;
    int m0 = bx * 64, n0 = by * 64;
    int am = t & 63, ac8 = t >> 6;
    int bn = t & 63, bkb = t >> 6;
    f32x4 acc[2][2] = {};
    bf16x8 rA, rB;
    auto loadA = [&](int k0) -> bf16x8 {
      if (m0 + am < 77) {
        const float* src = &ctx[(size_t)(m0 + am) * 768 + k0 + ac8 * 8];
        float4 x = *(const float4*)src;
        float4 y = *(const float4*)(src + 4);
        bf16x8 o;
        o[0] = (__bf16)x.x; o[1] = (__bf16)x.y; o[2] = (__bf16)x.z; o[3] = (__bf16)x.w;
        o[4] = (__bf16)y.x; o[5] = (__bf16)y.y; o[6] = (__bf16)y.z; o[7] = (__bf16)y.w;
        return o;
      }
      return zero8();
    };
    auto loadB = [&](int k0) {
      return *(const bf16x8*)&wKV2[((size_t)(k0 >> 3) + bkb) * (640 * 8) + (size_t)(n0 + bn) * 8];
    };
    rA = loadA(0); rB = loadB(0);
    *(bf16x8*)&sA[ac8 * 512 + am * 8] = rA;
    *(bf16x8*)&sB[bkb * 512 + bn * 8] = rB;
    __syncthreads();
    int cur = 0;
    for (int k0 = 0; k0 < 768; k0 += 32, cur ^= 1) {
      bool more = (k0 + 32) < 768;
      if (more) { rA = loadA(k0 + 32); rB = loadB(k0 + 32); }
      bf16x8 af[2], bfr[2];
#pragma unroll
      for (int fm = 0; fm < 2; ++fm)
        af[fm] = *(const bf16x8*)&sA[cur * 2048 + kb4 * 512 + (wr * 32 + fm * 16 + l15) * 8];
#pragma unroll
      for (int fn = 0; fn < 2; ++fn)
        bfr[fn] = *(const bf16x8*)&sB[cur * 2048 + kb4 * 512 + (wc * 32 + fn * 16 + l15) * 8];
#pragma unroll
      for (int fm = 0; fm < 2; ++fm)
#pragma unroll
        for (int fn = 0; fn < 2; ++fn) acc[fm][fn] = MFMA16(af[fm], bfr[fn], acc[fm][fn]);
      if (more) {
        *(bf16x8*)&sA[(cur ^ 1) * 2048 + ac8 * 512 + am * 8] = rA;
        *(bf16x8*)&sB[(cur ^ 1) * 2048 + bkb * 512 + bn * 8] = rB;
      }
      __syncthreads();
    }
#pragma unroll
    for (int fm = 0; fm < 2; ++fm)
#pragma unroll
      for (int fn = 0; fn < 2; ++fn)
#pragma unroll
        for (int r = 0; r < 4; ++r) {
          int row = m0 + wr * 32 + fm * 16 + kb4 * 4 + r;  // 0..127, rows>=77 exact 0
          int col = n0 + wc * 32 + fn * 16 + l15;
          float v = acc[fm][fn][r];
          if (col < 320) {
            int hh = col / 40, dh = col - hh * 40;
            scatterK(Kf2, 2, hh, row, dh, v);
          } else {
            int d = col - 320;
            int hh = d / 40, dh = d - hh * 40;
            scatterV(Vfl2, Vfh2, 2, hh, row, dh, v);
          }
        }
  }
}

// ---------------- GEGLU GEMM 64x64, BK=64, LN-on-load A, 1D + XCD swizzle -----
__global__ __launch_bounds__(256) void geglu64(const float* __restrict__ Hsrc,
                                               const float* __restrict__ rsi,
                                               const float* __restrict__ lng,
                                               const float* __restrict__ lnb,
                                               const __bf16* __restrict__ Bt,
                                               const float* __restrict__ bias,
                                               __bf16* __restrict__ Out) {
  __shared__ __align__(16) __bf16 sA[2][4096];
  __shared__ __align__(16) __bf16 sB[2][4096];
  __shared__ __align__(16) __bf16 sBg[2][4096];
  int t = threadIdx.x, lane = t & 63, wid = t >> 6;
  int wr = wid >> 1, wc = wid & 1, kb4 = lane >> 4, l15 = lane & 15;
  int id = blockIdx.x;
  int id2 = (id & 7) * 160 + (id >> 3);
  int bx = id2 / 20, by = id2 - bx * 20;
  int m0 = bx * 64, n0 = by * 64;
  f32x4 acc_a[2][2] = {}, acc_g[2][2] = {};
  int r0 = t >> 3, c0 = (t & 7) ^ (r0 & 7);
  float muA, rstdA, muB, rstdB;
  rowstat(rsi, m0 + r0, muA, rstdA);
  rowstat(rsi, m0 + 32 + r0, muB, rstdB);
  const float* hrowA = Hsrc + (size_t)(m0 + r0) * 320;
  const float* hrowB = Hsrc + (size_t)(m0 + 32 + r0) * 320;

  auto stage = [&](int buf, int k0) {
    int c = k0 + c0 * 8;
    *(bf16x8*)&sA[buf][(size_t)t * 8] = ln8(hrowA, c, muA, rstdA, lng, lnb);
    *(bf16x8*)&sA[buf][2048 + (size_t)t * 8] = ln8(hrowB, c, muB, rstdB, lng, lnb);
    gload16(&Bt[((size_t)(k0 >> 3) + wid) * (2560 * 8) + (size_t)(n0 + lane) * 8], &sB[buf][wid * 512]);
    gload16(&Bt[((size_t)(k0 >> 3) + wid + 4) * (2560 * 8) + (size_t)(n0 + lane) * 8], &sB[buf][2048 + wid * 512]);
    gload16(&Bt[((size_t)(k0 >> 3) + wid) * (2560 * 8) + (size_t)(1280 + n0 + lane) * 8], &sBg[buf][wid * 512]);
    gload16(&Bt[((size_t)(k0 >> 3) + wid + 4) * (2560 * 8) + (size_t)(1280 + n0 + lane) * 8], &sBg[buf][2048 + wid * 512]);
  };
  stage(0, 0);
  __syncthreads();
  int cur = 0;
  for (int k0 = 0; k0 < 320; k0 += 64) {
    if (k0 + 64 < 320) stage(cur ^ 1, k0 + 64);
#pragma unroll
    for (int kk = 0; kk < 2; ++kk) {
      int c8 = kb4 + kk * 4;
      bf16x8 af[2], bfa[2], bfg[2];
#pragma unroll
      for (int fm = 0; fm < 2; ++fm) {
        int row = wr * 32 + fm * 16 + l15;
        af[fm] = *(const bf16x8*)&sA[cur][row * 64 + ((c8 * 8) ^ ((row & 7) << 3))];
      }
#pragma unroll
      for (int fn = 0; fn < 2; ++fn) {
        bfa[fn] = *(const bf16x8*)&sB[cur][(c8 * 64 + wc * 32 + fn * 16 + l15) * 8];
        bfg[fn] = *(const bf16x8*)&sBg[cur][(c8 * 64 + wc * 32 + fn * 16 + l15) * 8];
      }
#pragma unroll
      for (int fm = 0; fm < 2; ++fm)
#pragma unroll
        for (int fn = 0; fn < 2; ++fn) {
          acc_a[fm][fn] = MFMA16(af[fm], bfa[fn], acc_a[fm][fn]);
          acc_g[fm][fn] = MFMA16(af[fm], bfg[fn], acc_g[fm][fn]);
        }
    }
    __syncthreads();
    cur ^= 1;
  }
#pragma unroll
  for (int fm = 0; fm < 2; ++fm)
#pragma unroll
    for (int fn = 0; fn < 2; ++fn)
#pragma unroll
      for (int r = 0; r < 4; ++r) {
        int row = m0 + wr * 32 + fm * 16 + kb4 * 4 + r;
        int col = n0 + wc * 32 + fn * 16 + l15;
        float a = acc_a[fm][fn][r] + bias[col];
        float g = acc_g[fm][fn][r] + bias[1280 + col];
        Out[(size_t)row * 1280 + col] = (__bf16)(a * gelu_exact(g));
      }
}

// ---------------- flash attention: register-direct K/V, dual-q per wave ------
__global__ __launch_bounds__(512) void attn_kernel(const __bf16* __restrict__ Qh,
                                                   const __bf16* __restrict__ Kf,
                                                   const __bf16* __restrict__ Vfl,
                                                   const __bf16* __restrict__ Vfh,
                                                   __bf16* __restrict__ Oh,
                                                   int kv_len, int NT) {
  __shared__ float sO[12288];  // [4 slot][2 qg][64 lane][24]
  int t = threadIdx.x, lane = t & 63, wid = t >> 6;
  int zz = wid >> 1, kg = wid & 1;
  int l31 = lane & 31, hi = lane >> 5;
  int id2 = ((blockIdx.x & 7) << 6) | (blockIdx.x >> 3);
  int h = id2 >> 6, q0 = (id2 & 63) * 64;

  bf16x8 qf0[3], qf1[3];
  {
    const __bf16* qr0 = Qh + ((size_t)h * 4096 + q0 + l31) * 48;
    const __bf16* qr1 = Qh + ((size_t)h * 4096 + q0 + 32 + l31) * 48;
#pragma unroll
    for (int s = 0; s < 3; ++s) {
      qf0[s] = *(const bf16x8*)(qr0 + s * 16 + hi * 8);
      qf1[s] = *(const bf16x8*)(qr1 + s * 16 + hi * 8);
    }
  }
  bf16x8 vfill = (l31 == 8) ? ones8() : zero8();  // d=40 ones-row (l accumulator)
  f32x16 oL0 = {}, oH0 = {}, oL1 = {}, oH1 = {};

  int half = (NT >= 4) ? (NT >> 2) : 1;
  int t0 = zz * half; if (t0 > NT) t0 = NT;
  int t1 = t0 + half; if (t1 > NT) t1 = NT;
  for (int tile = t0; tile < t1; ++tile) {
    size_t kb = ((size_t)h * NT + tile) * 2 + kg;
    const __bf16* kp = Kf + kb * 1536 + lane * 8;
    bf16x8 kf0 = *(const bf16x8*)(kp);
    bf16x8 kf1 = *(const bf16x8*)(kp + 512);
    bf16x8 kf2 = *(const bf16x8*)(kp + 1024);
    const __bf16* vp = Vfl + kb * 1024 + lane * 8;
    bf16x8 vl0 = *(const bf16x8*)(vp);
    bf16x8 vl1 = *(const bf16x8*)(vp + 512);
    bf16x8 vh0 = vfill, vh1 = vfill;
    if (l31 < 8) {
      const __bf16* vph = Vfh + kb * 256 + (hi * 8 + l31) * 8;
      vh0 = *(const bf16x8*)(vph);
      vh1 = *(const bf16x8*)(vph + 128);
    }
    // two independent S^T chains sharing K fragments
    f32x16 s0 = {}, s1 = {};
    __builtin_amdgcn_s_setprio(1);
    s0 = MFMA32(kf0, qf0[0], s0);
    s1 = MFMA32(kf0, qf1[0], s1);
    s0 = MFMA32(kf1, qf0[1], s0);
    s1 = MFMA32(kf1, qf1[1], s1);
    s0 = MFMA32(kf2, qf0[2], s0);
    s1 = MFMA32(kf2, qf1[2], s1);
    __builtin_amdgcn_s_setprio(0);
    int k0 = tile << 6;
    if (k0 + 64 > kv_len) {
#pragma unroll
      for (int r = 0; r < 16; ++r) {
        int klo = (r & 3) + 8 * (r >> 2) + 4 * hi;
        if (k0 + kg * 32 + klo >= kv_len) { s0[r] = -1e30f; s1[r] = -1e30f; }
      }
    }
    bf16x8 p00, p01, p10, p11;
#pragma unroll
    for (int j = 0; j < 8; ++j) {
      p00[j] = (__bf16)fexp2(s0[j]);
      p01[j] = (__bf16)fexp2(s0[8 + j]);
      p10[j] = (__bf16)fexp2(s1[j]);
      p11[j] = (__bf16)fexp2(s1[8 + j]);
    }
    __builtin_amdgcn_s_setprio(1);
    oL0 = MFMA32(vl0, p00, oL0);
    oL1 = MFMA32(vl0, p10, oL1);
    oH0 = MFMA32(vh0, p00, oH0);
    oH1 = MFMA32(vh0, p10, oH1);
    oL0 = MFMA32(vl1, p01, oL0);
    oL1 = MFMA32(vl1, p11, oL1);
    oH0 = MFMA32(vh1, p01, oH0);
    oH1 = MFMA32(vh1, p11, oH1);
    __builtin_amdgcn_s_setprio(0);
  }
  // 2-phase in-block combine across the 8 (zz,kg) sources.
  int srcid = zz * 2 + kg;  // 0..7
  auto dumpTo = [&](int slot, const f32x16& ol, const f32x16& oh, int qg) {
    float* dst = sO + (((size_t)slot * 2 + qg) * 64 + lane) * 24;
#pragma unroll
    for (int r = 0; r < 16; ++r) dst[r] = ol[r];
#pragma unroll
    for (int r = 0; r < 4; ++r) dst[16 + r] = oh[r];
    dst[20] = oh[4];
  };
  auto addFrom = [&](int slot, f32x16& ol, f32x16& oh, int qg) {
    const float* sp = sO + (((size_t)slot * 2 + qg) * 64 + lane) * 24;
#pragma unroll
    for (int r = 0; r < 16; ++r) ol[r] += sp[r];
#pragma unroll
    for (int r = 0; r < 4; ++r) oh[r] += sp[16 + r];
    oh[4] += sp[20];
  };
  // phase 1: srcid 4..7 dump; srcid 0..3 absorb their +4 counterpart
  if (srcid >= 4) { dumpTo(srcid - 4, oL0, oH0, 0); dumpTo(srcid - 4, oL1, oH1, 1); }
  __syncthreads();
  if (srcid < 4) { addFrom(srcid, oL0, oH0, 0); addFrom(srcid, oL1, oH1, 1); }
  __syncthreads();
  // phase 2: srcid 1..3 dump; srcid 0 sums + finalizes
  if (srcid >= 1 && srcid < 4) { dumpTo(srcid - 1, oL0, oH0, 0); dumpTo(srcid - 1, oL1, oH1, 1); }
  __syncthreads();
  if (srcid == 0) {
#pragma unroll
    for (int src = 0; src < 3; ++src) { addFrom(src, oL0, oH0, 0); addFrom(src, oL1, oH1, 1); }
#pragma unroll
    for (int qg = 0; qg < 2; ++qg) {
      const f32x16& ol = qg ? oL1 : oL0;
      const f32x16& oh = qg ? oH1 : oH0;
      float ls = __shfl(oh[4], l31);  // l for q at lane l31 (hi=0), reg 4
      float inv = 1.0f / ls;
      __bf16* orow = Oh + ((size_t)h * 4096 + q0 + qg * 32 + l31) * 40;
#pragma unroll
      for (int r = 0; r < 16; r += 2) {
        int d = (r & 3) + 8 * (r >> 2) + 4 * hi;
        bf16x2 o2;
        o2[0] = (__bf16)(ol[r] * inv);
        o2[1] = (__bf16)(ol[r + 1] * inv);
        *(bf16x2*)(orow + d) = o2;
      }
#pragma unroll
      for (int r = 0; r < 4; r += 2) {
        int d = 32 + r + 4 * hi;
        bf16x2 o2;
        o2[0] = (__bf16)(oh[r] * inv);
        o2[1] = (__bf16)(oh[r + 1] * inv);
        *(bf16x2*)(orow + d) = o2;
      }
    }
  }
}

// =============================================================================
extern "C" void kernel_launch(void* const* d_in, const int* in_sizes, int n_in,
                              void* d_out, int out_size, void* d_ws, size_t ws_size,
                              hipStream_t stream) {
  const float* hs    = (const float*)d_in[0];
  const float* ctx   = (const float*)d_in[1];
  const float* gn_g  = (const float*)d_in[2];
  const float* gn_b  = (const float*)d_in[3];
  const float* pi_w  = (const float*)d_in[4];
  const float* pi_b  = (const float*)d_in[5];
  const float* n1_g  = (const float*)d_in[6];
  const float* n1_b  = (const float*)d_in[7];
  const float* a1_q  = (const float*)d_in[8];
  const float* a1_k  = (const float*)d_in[9];
  const float* a1_v  = (const float*)d_in[10];
  const float* a1_o  = (const float*)d_in[11];
  const float* a1_ob = (const float*)d_in[12];
  const float* n2_g  = (const float*)d_in[13];
  const float* n2_b  = (const float*)d_in[14];
  const float* a2_q  = (const float*)d_in[15];
  const float* a2_k  = (const float*)d_in[16];
  const float* a2_v  = (const float*)d_in[17];
  const float* a2_o  = (const float*)d_in[18];
  const float* a2_ob = (const float*)d_in[19];
  const float* n3_g  = (const float*)d_in[20];
  const float* n3_b  = (const float*)d_in[21];
  const float* ff_w1 = (const float*)d_in[22];
  const float* ff_b1 = (const float*)d_in[23];
  const float* ff_w2 = (const float*)d_in[24];
  const float* ff_b2 = (const float*)d_in[25];
  const float* po_w  = (const float*)d_in[26];
  const float* po_b  = (const float*)d_in[27];

  char* p = (char*)d_ws;
  auto alloc = [&](size_t bytes) {
    char* r = p;
    p += (bytes + 255) & ~(size_t)255;
    return r;
  };
  __bf16* wPI  = (__bf16*)alloc((size_t)320 * 320 * 2);
  __bf16* wQKV = (__bf16*)alloc((size_t)320 * 960 * 2);
  __bf16* wO1  = (__bf16*)alloc((size_t)320 * 320 * 2);
  __bf16* wQ2  = (__bf16*)alloc((size_t)320 * 320 * 2);
  __bf16* wKV2 = (__bf16*)alloc((size_t)768 * 640 * 2);
  __bf16* wO2  = (__bf16*)alloc((size_t)320 * 320 * 2);
  __bf16* wFF1 = (__bf16*)alloc((size_t)320 * 2560 * 2);
  __bf16* wFF2 = (__bf16*)alloc((size_t)1280 * 320 * 2);
  __bf16* wPO  = (__bf16*)alloc((size_t)320 * 320 * 2);

  float*  gpart= (float*)alloc((size_t)256 * 2 * 4);
  float*  rsall= (float*)alloc((size_t)24576 * 4);  // 3 x [4096][2] LN stats
  float*  rs1  = rsall;
  float*  rs2  = rsall + 8192;
  float*  rs3  = rsall + 16384;
  __bf16* xg   = (__bf16*)alloc((size_t)4096 * 320 * 2);
  float*  h    = (float*)alloc((size_t)4096 * 320 * 4);
  __bf16* hb   = (__bf16*)alloc((size_t)4096 * 320 * 2);
  __bf16* qh   = (__bf16*)alloc((size_t)8 * 4096 * 48 * 2);
  __bf16* kf   = (__bf16*)alloc((size_t)8 * 64 * 2 * 3 * 512 * 2);
  __bf16* vfl  = (__bf16*)alloc((size_t)8 * 64 * 2 * 2 * 512 * 2);
  __bf16* vfh  = (__bf16*)alloc((size_t)8 * 64 * 2 * 2 * 128 * 2);
  __bf16* kf2  = (__bf16*)alloc((size_t)8 * 2 * 2 * 3 * 512 * 2);
  __bf16* vfl2 = (__bf16*)alloc((size_t)8 * 2 * 2 * 2 * 512 * 2);
  __bf16* vfh2 = (__bf16*)alloc((size_t)8 * 2 * 2 * 2 * 128 * 2);
  __bf16* oh   = (__bf16*)alloc((size_t)4096 * 320 * 2);
  __bf16* g    = (__bf16*)alloc((size_t)4096 * 1280 * 2);
  float*  outp = (float*)d_out;

  // 1. prep: wconv (0..4799) + GN stats (4800..5055) + zero LN stats (5056..5067)
  WTable tab;
  tab.w[0]  = WDesc{pi_w,  wPI,  320, 320, 320, 0};
  tab.w[1]  = WDesc{a1_q,  wQKV, 320, 320, 960, 0};
  tab.w[2]  = WDesc{a1_k,  wQKV, 320, 320, 960, 320};
  tab.w[3]  = WDesc{a1_v,  wQKV, 320, 320, 960, 640};
  tab.w[4]  = WDesc{a1_o,  wO1,  320, 320, 320, 0};
  tab.w[5]  = WDesc{a2_q,  wQ2,  320, 320, 320, 0};
  tab.w[6]  = WDesc{a2_k,  wKV2, 768, 320, 640, 0};
  tab.w[7]  = WDesc{a2_v,  wKV2, 768, 320, 640, 320};
  tab.w[8]  = WDesc{a2_o,  wO2,  320, 320, 320, 0};
  tab.w[9]  = WDesc{ff_w1, wFF1, 320, 2560, 2560, 0};
  tab.w[10] = WDesc{ff_w2, wFF2, 1280, 320, 320, 0};
  tab.w[11] = WDesc{po_w,  wPO,  320, 320, 320, 0};
  prep_kernel<<<dim3(5068), 256, 0, stream>>>(tab, hs, gpart, rsall);
  // 2. groupnorm apply -> xg bf16 [px][c]
  gn_apply<<<dim3(640), 256, 0, stream>>>(hs, gpart, gn_g, gn_b, xg);
  // 3. proj_in -> h (+ LN1 stats)
  gemm32<0, true, false, false, false, true, false><<<dim3(640), 256, 0, stream>>>(
      xg, wPI, pi_b, nullptr, h, nullptr, 4096, 320, 320, rs1, nullptr, nullptr, nullptr, nullptr);
  // 4. merged QKV (LN1 on load) + cross-K/V
  qkv_gemm<<<dim3(980), 256, 0, stream>>>(h, rs1, n1_g, n1_b, wQKV, qh, kf, vfl, vfh,
                                          ctx, wKV2, kf2, vfl2, vfh2);
  // 5. self attention
  attn_kernel<<<dim3(512), 512, 0, stream>>>(qh, kf, vfl, vfh, oh, 4096, 64);
  // 6. out proj + residual -> h (+ LN2 stats)
  gemm32<0, true, true, false, true, true, false><<<dim3(640), 256, 0, stream>>>(
      oh, wO1, a1_ob, h, h, nullptr, 4096, 320, 320, rs2, nullptr, nullptr, nullptr, nullptr);
  // 7. cross q (LN2 on load, head-blocked pad-48, scaled)
  gemm32<4, false, false, true, false, false, true><<<dim3(640), 256, 0, stream>>>(
      nullptr, wQ2, nullptr, nullptr, qh, nullptr, 4096, 320, 320, nullptr, h, rs2, n2_g, n2_b);
  // 8. cross attention
  attn_kernel<<<dim3(512), 512, 0, stream>>>(qh, kf2, vfl2, vfh2, oh, 77, 2);
  // 9. out proj + residual -> h (+ LN3 stats)
  gemm32<0, true, true, false, true, true, false><<<dim3(640), 256, 0, stream>>>(
      oh, wO2, a2_ob, h, h, nullptr, 4096, 320, 320, rs3, nullptr, nullptr, nullptr, nullptr);
  // 10. GEGLU (LN3 on load)
  geglu64<<<dim3(1280), 256, 0, stream>>>(h, rs3, n3_g, n3_b, wFF1, ff_b1, g);
  // 11. FF2 + residual -> h f32 + hb bf16
  gemm32<2, true, true, false, false, false, false><<<dim3(640), 256, 0, stream>>>(
      g, wFF2, ff_b2, h, h, hb, 4096, 320, 1280, nullptr, nullptr, nullptr, nullptr, nullptr);
  // 12. proj_out (transposed) + input residual -> d_out
  gemm32<3, true, true, false, false, false, false><<<dim3(640), 256, 0, stream>>>(
      hb, wPO, po_b, hs, outp, nullptr, 4096, 320, 320, nullptr, nullptr, nullptr, nullptr, nullptr);
}

// Round 18
// 155.324 us; speedup vs baseline: 1.0124x; 1.0124x over previous
//
#include <hip/hip_runtime.h>

typedef __bf16 bf16x8 __attribute__((ext_vector_type(8)));
typedef __bf16 bf16x4 __attribute__((ext_vector_type(4)));
typedef __bf16 bf16x2 __attribute__((ext_vector_type(2)));
typedef float f32x4 __attribute__((ext_vector_type(4)));
typedef float f32x16 __attribute__((ext_vector_type(16)));

#define MFMA16(a, b, c) __builtin_amdgcn_mfma_f32_16x16x32_bf16(a, b, c, 0, 0, 0)
#define MFMA32(a, b, c) __builtin_amdgcn_mfma_f32_32x32x16_bf16(a, b, c, 0, 0, 0)

// ATT_SCALE * log2(e): Q projection pre-scaled so softmax uses exp2 directly.
static constexpr float QSCALE = 0.15811388300841897f * 1.4426950408889634f;

// raw v_exp_f32 (exp2f without OCML denormal-range wrapper; scores are bounded)
__device__ __forceinline__ float fexp2(float x) { return __builtin_amdgcn_exp2f(x); }

// direct global->LDS DMA, 16B per lane. LDS dst must be wave-uniform base.
__device__ __forceinline__ void gload16(const __bf16* g, __bf16* l) {
  __builtin_amdgcn_global_load_lds((const __attribute__((address_space(1))) void*)g,
                                   (__attribute__((address_space(3))) void*)l, 16, 0, 0);
}

__device__ __forceinline__ bf16x8 zero8() {
  bf16x8 z;
#pragma unroll
  for (int j = 0; j < 8; ++j) z[j] = (__bf16)0.0f;
  return z;
}

__device__ __forceinline__ bf16x8 ones8() {
  bf16x8 z;
#pragma unroll
  for (int j = 0; j < 8; ++j) z[j] = (__bf16)1.0f;
  return z;
}

__device__ __forceinline__ float gelu_exact(float x) {
  return 0.5f * x * (1.0f + erff(x * 0.70710678118654752f));
}

// ---------------- prep: weight transpose-convert + GN stats (merged) ----------
struct WDesc { const float* src; __bf16* dst; int K; int N; int ldn; int noff; };
struct WTable { WDesc w[12]; };

__global__ __launch_bounds__(256) void prep_kernel(WTable tab,
                                                   const float* __restrict__ X,
                                                   float* __restrict__ part) {
  __shared__ float rs[4], rs2[4];
  int id = blockIdx.x;
  if (id < 4800) {
    WDesc d = tab.w[id / 400];
    int total = (d.K >> 3) * d.N;
    int idx = (id % 400) * 256 + threadIdx.x;
    if (idx >= total) return;
    int kb = idx / d.N, n = idx - kb * d.N;
    bf16x8 o;
#pragma unroll
    for (int j = 0; j < 8; ++j) o[j] = (__bf16)d.src[(size_t)(kb * 8 + j) * d.N + n];
    *(bf16x8*)&d.dst[((size_t)kb * d.ldn + d.noff + n) * 8] = o;
  } else {
    int gb = id - 4800;  // 0..255
    int g = gb >> 3, cid = gb & 7;
    const float* base = X + (size_t)g * 40960 + (size_t)cid * 5120;
    int t = threadIdx.x;
    float s = 0.f, s2 = 0.f;
#pragma unroll
    for (int i = t; i < 1280; i += 256) {
      float4 v = ((const float4*)base)[i];
      s += v.x + v.y + v.z + v.w;
      s2 += v.x * v.x + v.y * v.y + v.z * v.z + v.w * v.w;
    }
#pragma unroll
    for (int off = 1; off < 64; off <<= 1) { s += __shfl_xor(s, off); s2 += __shfl_xor(s2, off); }
    int wid = t >> 6, lane = t & 63;
    if (lane == 0) { rs[wid] = s; rs2[wid] = s2; }
    __syncthreads();
    if (t == 0) {
      part[gb * 2] = rs[0] + rs[1] + rs[2] + rs[3];
      part[gb * 2 + 1] = rs2[0] + rs2[1] + rs2[2] + rs2[3];
    }
  }
}

__global__ __launch_bounds__(256) void gn_apply(const float* __restrict__ X,
                                                const float* __restrict__ part,
                                                const float* __restrict__ gg,
                                                const float* __restrict__ gb,
                                                __bf16* __restrict__ Y) {
  int i0 = (blockIdx.x * 256 + threadIdx.x) * 8;
  int c = i0 >> 12, px = i0 & 4095;
  int g = c / 10;
  float s = 0.f, s2 = 0.f;
#pragma unroll
  for (int j = 0; j < 8; ++j) { s += part[(g * 8 + j) * 2]; s2 += part[(g * 8 + j) * 2 + 1]; }
  float mu = s * (1.f / 40960.f);
  float rstd = rsqrtf(s2 * (1.f / 40960.f) - mu * mu + 1e-6f);
  float ga = gg[c] * rstd, bb = gb[c] - mu * ga;
  float4 a = *(const float4*)&X[i0];
  float4 b = *(const float4*)&X[i0 + 4];
  Y[(size_t)(px + 0) * 320 + c] = (__bf16)(a.x * ga + bb);
  Y[(size_t)(px + 1) * 320 + c] = (__bf16)(a.y * ga + bb);
  Y[(size_t)(px + 2) * 320 + c] = (__bf16)(a.z * ga + bb);
  Y[(size_t)(px + 3) * 320 + c] = (__bf16)(a.w * ga + bb);
  Y[(size_t)(px + 4) * 320 + c] = (__bf16)(b.x * ga + bb);
  Y[(size_t)(px + 5) * 320 + c] = (__bf16)(b.y * ga + bb);
  Y[(size_t)(px + 6) * 320 + c] = (__bf16)(b.z * ga + bb);
  Y[(size_t)(px + 7) * 320 + c] = (__bf16)(b.w * ga + bb);
}

// ---------------- LayerNorm fp32 [4096,320] -> bf16 --------------------------
__global__ __launch_bounds__(256) void ln_kernel(const float* __restrict__ X,
                                                 const float* __restrict__ g,
                                                 const float* __restrict__ b,
                                                 __bf16* __restrict__ Y) {
  int row = blockIdx.x * 4 + (threadIdx.x >> 6);
  int lane = threadIdx.x & 63;
  const float* x = X + (size_t)row * 320;
  float v[5];
  float s = 0.f;
#pragma unroll
  for (int i = 0; i < 5; ++i) { v[i] = x[lane + 64 * i]; s += v[i]; }
#pragma unroll
  for (int off = 1; off < 64; off <<= 1) s += __shfl_xor(s, off);
  float mu = s * (1.f / 320.f);
  float s2 = 0.f;
#pragma unroll
  for (int i = 0; i < 5; ++i) { float d = v[i] - mu; s2 += d * d; }
#pragma unroll
  for (int off = 1; off < 64; off <<= 1) s2 += __shfl_xor(s2, off);
  float rstd = rsqrtf(s2 * (1.f / 320.f) + 1e-5f);
#pragma unroll
  for (int i = 0; i < 5; ++i) {
    int c = lane + 64 * i;
    Y[(size_t)row * 320 + c] = (__bf16)((v[i] - mu) * rstd * g[c] + b[c]);
  }
}

// ---------------- 32x64 bf16 GEMM, BK=64, 1D grid + XCD chunk swizzle ---------
// OM: 0=f32 out, 1=bf16 out, 2=f32+bf16, 3=transposed f32, 4=head-blocked pad48.
template <int OM, bool HB, bool HR, bool QS, bool AH>
__global__ __launch_bounds__(256) void gemm32(const __bf16* __restrict__ A,
                                              const __bf16* __restrict__ Bt,
                                              const float* __restrict__ bias,
                                              const float* __restrict__ res,
                                              void* __restrict__ Cout,
                                              void* __restrict__ Cout2,
                                              int M, int N, int K) {
  __shared__ __align__(16) __bf16 sA[2][2048];
  __shared__ __align__(16) __bf16 sB[2][4096];
  int t = threadIdx.x, lane = t & 63, wid = t >> 6;
  int wr = wid >> 1, wc = wid & 1, kb4 = lane >> 4, l15 = lane & 15;
  int id = blockIdx.x;
  int id2 = (id & 7) * 80 + (id >> 3);
  int bx = id2 / 5, by = id2 - bx * 5;
  int m0 = bx * 32, n0 = by * 64;
  const size_t N8 = (size_t)N * 8;
  f32x4 acc[2] = {};
  int r0 = t >> 3, c0 = (t & 7) ^ (r0 & 7);

  auto stage = [&](int buf, int k0) {
    const __bf16* ga0;
    if (AH) {
      int kk = k0 + c0 * 8;
      int hh = kk / 40, dh = kk - hh * 40;
      ga0 = &A[((size_t)hh * 4096 + m0 + r0) * 40 + dh];
    } else {
      ga0 = &A[(size_t)(m0 + r0) * K + k0 + c0 * 8];
    }
    gload16(ga0, &sA[buf][wid * 512]);
    gload16(&Bt[((size_t)(k0 >> 3) + wid) * N8 + (size_t)(n0 + lane) * 8], &sB[buf][wid * 512]);
    gload16(&Bt[((size_t)(k0 >> 3) + wid + 4) * N8 + (size_t)(n0 + lane) * 8], &sB[buf][2048 + wid * 512]);
  };
  stage(0, 0);
  __syncthreads();
  int cur = 0;
  for (int k0 = 0; k0 < K; k0 += 64) {
    if (k0 + 64 < K) stage(cur ^ 1, k0 + 64);
#pragma unroll
    for (int kk = 0; kk < 2; ++kk) {
      int c8 = kb4 + kk * 4;
      int row = wr * 16 + l15;
      bf16x8 af = *(const bf16x8*)&sA[cur][row * 64 + ((c8 * 8) ^ ((row & 7) << 3))];
      bf16x8 bfr[2];
#pragma unroll
      for (int fn = 0; fn < 2; ++fn)
        bfr[fn] = *(const bf16x8*)&sB[cur][(c8 * 64 + wc * 32 + fn * 16 + l15) * 8];
#pragma unroll
      for (int fn = 0; fn < 2; ++fn) acc[fn] = MFMA16(af, bfr[fn], acc[fn]);
    }
    __syncthreads();
    cur ^= 1;
  }
#pragma unroll
  for (int fn = 0; fn < 2; ++fn)
#pragma unroll
    for (int r = 0; r < 4; ++r) {
      int row = m0 + wr * 16 + kb4 * 4 + r;
      int col = n0 + wc * 32 + fn * 16 + l15;
      float v = acc[fn][r];
      if (HB) v += bias[col];
      if (OM == 3) {
        if (HR) v += res[(size_t)col * M + row];
        ((float*)Cout)[(size_t)col * M + row] = v;
      } else if (OM == 4) {
        int hh = col / 40, dh = col - hh * 40;
        __bf16* qp = (__bf16*)Cout + ((size_t)hh * 4096 + row) * 48 + dh;
        *qp = (__bf16)(QS ? v * QSCALE : v);
        if (dh >= 32) qp[8] = (__bf16)0.f;
      } else {
        if (HR) v += res[(size_t)row * N + col];
        if (OM == 0) {
          ((float*)Cout)[(size_t)row * N + col] = v;
        } else if (OM == 1) {
          ((__bf16*)Cout)[(size_t)row * N + col] = (__bf16)(QS ? v * QSCALE : v);
        } else {
          ((float*)Cout)[(size_t)row * N + col] = v;
          ((__bf16*)Cout2)[(size_t)row * N + col] = (__bf16)v;
        }
      }
    }
}

// ---- K/V fragment-order scatter helpers (write side of register-direct attn) -
__device__ __forceinline__ void scatterK(__bf16* Kf, int NT, int hh, int row, int dh, float v) {
  int tile = row >> 6, kg = (row >> 5) & 1, k31 = row & 31;
  int s = dh >> 4, hi = (dh >> 3) & 1, j = dh & 7;
  size_t base = (((size_t)hh * NT + tile) * 2 + kg) * 3;
  Kf[(base + s) * 512 + (hi * 32 + k31) * 8 + j] = (__bf16)v;
  if (dh >= 32)  // zero-fill the d=40..47 slice (s=2, hi=1)
    Kf[(base + 2) * 512 + (32 + k31) * 8 + (dh & 7)] = (__bf16)0.f;
}
__device__ __forceinline__ void scatterV(__bf16* Vfl, __bf16* Vfh, int NT, int hh,
                                         int row, int dh, float v) {
  int tile = row >> 6, kg = (row >> 5) & 1, klo = row & 31;
  int m = (klo >> 4) & 1, hik = (klo >> 2) & 1;
  int jj = (klo & 3) | (((klo >> 3) & 1) << 2);
  size_t base = (((size_t)hh * NT + tile) * 2 + kg) * 2 + m;
  if (dh < 32) Vfl[base * 512 + (hik * 32 + dh) * 8 + jj] = (__bf16)v;
  else Vfh[base * 128 + (hik * 8 + (dh - 32)) * 8 + jj] = (__bf16)v;
}

// ---------------- merged QKV GEMM (blocks 0..959) + cross-K/V GEMM (960..979) -
__global__ __launch_bounds__(256) void qkv_gemm(const __bf16* __restrict__ A,
                                                const __bf16* __restrict__ Bt,
                                                __bf16* __restrict__ Qh,
                                                __bf16* __restrict__ Kf,
                                                __bf16* __restrict__ Vfl,
                                                __bf16* __restrict__ Vfh,
                                                const float* __restrict__ ctx,
                                                const __bf16* __restrict__ wKV2,
                                                __bf16* __restrict__ Kf2,
                                                __bf16* __restrict__ Vfl2,
                                                __bf16* __restrict__ Vfh2) {
  __shared__ __align__(16) char smem[32768];
  __bf16* sA = (__bf16*)smem;            // qkv: [2][4096]; kv2: [2][2048]
  __bf16* sB = (__bf16*)(smem + 16384);  // qkv: [2][4096]; kv2: [2][2048]
  int t = threadIdx.x, lane = t & 63, wid = t >> 6;
  int wr = wid >> 1, wc = wid & 1, kb4 = lane >> 4, l15 = lane & 15;

  if (blockIdx.x < 960) {
    int id = blockIdx.x;
    int id2 = (id & 7) * 120 + (id >> 3);
    int bx = id2 / 15, by = id2 - bx * 15;
    int m0 = bx * 64, n0 = by * 64;
    f32x4 acc[2][2] = {};
    int r0 = t >> 3, c0 = (t & 7) ^ (r0 & 7);

    auto stage = [&](int buf, int k0) {
      gload16(&A[(size_t)(m0 + r0) * 320 + k0 + c0 * 8], &sA[buf * 4096 + wid * 512]);
      gload16(&A[(size_t)(m0 + 32 + r0) * 320 + k0 + c0 * 8], &sA[buf * 4096 + 2048 + wid * 512]);
      gload16(&Bt[((size_t)(k0 >> 3) + wid) * (960 * 8) + (size_t)(n0 + lane) * 8], &sB[buf * 4096 + wid * 512]);
      gload16(&Bt[((size_t)(k0 >> 3) + wid + 4) * (960 * 8) + (size_t)(n0 + lane) * 8], &sB[buf * 4096 + 2048 + wid * 512]);
    };
    stage(0, 0);
    __syncthreads();
    int cur = 0;
    for (int k0 = 0; k0 < 320; k0 += 64) {
      if (k0 + 64 < 320) stage(cur ^ 1, k0 + 64);
#pragma unroll
      for (int kk = 0; kk < 2; ++kk) {
        int c8 = kb4 + kk * 4;
        bf16x8 af[2], bfr[2];
#pragma unroll
        for (int fm = 0; fm < 2; ++fm) {
          int row = wr * 32 + fm * 16 + l15;
          af[fm] = *(const bf16x8*)&sA[cur * 4096 + row * 64 + ((c8 * 8) ^ ((row & 7) << 3))];
        }
#pragma unroll
        for (int fn = 0; fn < 2; ++fn)
          bfr[fn] = *(const bf16x8*)&sB[cur * 4096 + (c8 * 64 + wc * 32 + fn * 16 + l15) * 8];
#pragma unroll
        for (int fm = 0; fm < 2; ++fm)
#pragma unroll
          for (int fn = 0; fn < 2; ++fn) acc[fm][fn] = MFMA16(af[fm], bfr[fn], acc[fm][fn]);
      }
      __syncthreads();
      cur ^= 1;
    }
#pragma unroll
    for (int fm = 0; fm < 2; ++fm)
#pragma unroll
      for (int fn = 0; fn < 2; ++fn)
#pragma unroll
        for (int r = 0; r < 4; ++r) {
          int row = m0 + wr * 32 + fm * 16 + kb4 * 4 + r;
          int col = n0 + wc * 32 + fn * 16 + l15;
          float v = acc[fm][fn][r];
          if (col < 320) {
            int hh = col / 40, dh = col - hh * 40;
            __bf16* qp = &Qh[((size_t)hh * 4096 + row) * 48 + dh];
            *qp = (__bf16)(v * QSCALE);
            if (dh >= 32) qp[8] = (__bf16)0.f;
          } else if (col < 640) {
            int d = col - 320;
            int hh = d / 40, dh = d - hh * 40;
            scatterK(Kf, 64, hh, row, dh, v);
          } else {
            int d = col - 640;
            int hh = d / 40, dh = d - hh * 40;
            scatterV(Vfl, Vfh, 64, hh, row, dh, v);
          }
        }
  } else {
    // ---- cross K/V GEMM: 20 blocks (bx in 0..1, by in 0..9) ----
    int id2 = blockIdx.x - 960;
    int bx = id2 & 1, by = id2 >> 1;
    int m0 = bx * 64, n0 = by * 64;
    int am = t & 63, ac8 = t >> 6;
    int bn = t & 63, bkb = t >> 6;
    f32x4 acc[2][2] = {};
    bf16x8 rA, rB;
    auto loadA = [&](int k0) -> bf16x8 {
      if (m0 + am < 77) {
        const float* src = &ctx[(size_t)(m0 + am) * 768 + k0 + ac8 * 8];
        float4 x = *(const float4*)src;
        float4 y = *(const float4*)(src + 4);
        bf16x8 o;
        o[0] = (__bf16)x.x; o[1] = (__bf16)x.y; o[2] = (__bf16)x.z; o[3] = (__bf16)x.w;
        o[4] = (__bf16)y.x; o[5] = (__bf16)y.y; o[6] = (__bf16)y.z; o[7] = (__bf16)y.w;
        return o;
      }
      return zero8();
    };
    auto loadB = [&](int k0) {
      return *(const bf16x8*)&wKV2[((size_t)(k0 >> 3) + bkb) * (640 * 8) + (size_t)(n0 + bn) * 8];
    };
    rA = loadA(0); rB = loadB(0);
    *(bf16x8*)&sA[ac8 * 512 + am * 8] = rA;
    *(bf16x8*)&sB[bkb * 512 + bn * 8] = rB;
    __syncthreads();
    int cur = 0;
    for (int k0 = 0; k0 < 768; k0 += 32, cur ^= 1) {
      bool more = (k0 + 32) < 768;
      if (more) { rA = loadA(k0 + 32); rB = loadB(k0 + 32); }
      bf16x8 af[2], bfr[2];
#pragma unroll
      for (int fm = 0; fm < 2; ++fm)
        af[fm] = *(const bf16x8*)&sA[cur * 2048 + kb4 * 512 + (wr * 32 + fm * 16 + l15) * 8];
#pragma unroll
      for (int fn = 0; fn < 2; ++fn)
        bfr[fn] = *(const bf16x8*)&sB[cur * 2048 + kb4 * 512 + (wc * 32 + fn * 16 + l15) * 8];
#pragma unroll
      for (int fm = 0; fm < 2; ++fm)
#pragma unroll
        for (int fn = 0; fn < 2; ++fn) acc[fm][fn] = MFMA16(af[fm], bfr[fn], acc[fm][fn]);
      if (more) {
        *(bf16x8*)&sA[(cur ^ 1) * 2048 + ac8 * 512 + am * 8] = rA;
        *(bf16x8*)&sB[(cur ^ 1) * 2048 + bkb * 512 + bn * 8] = rB;
      }
      __syncthreads();
    }
#pragma unroll
    for (int fm = 0; fm < 2; ++fm)
#pragma unroll
      for (int fn = 0; fn < 2; ++fn)
#pragma unroll
        for (int r = 0; r < 4; ++r) {
          int row = m0 + wr * 32 + fm * 16 + kb4 * 4 + r;  // 0..127, rows>=77 exact 0
          int col = n0 + wc * 32 + fn * 16 + l15;
          float v = acc[fm][fn][r];
          if (col < 320) {
            int hh = col / 40, dh = col - hh * 40;
            scatterK(Kf2, 2, hh, row, dh, v);
          } else {
            int d = col - 320;
            int hh = d / 40, dh = d - hh * 40;
            scatterV(Vfl2, Vfh2, 2, hh, row, dh, v);
          }
        }
  }
}

// ---------------- GEGLU GEMM 64x64, BK=64, 1D grid + XCD chunk swizzle --------
__global__ __launch_bounds__(256) void geglu64(const __bf16* __restrict__ A,
                                               const __bf16* __restrict__ Bt,
                                               const float* __restrict__ bias,
                                               __bf16* __restrict__ Out) {
  __shared__ __align__(16) __bf16 sA[2][4096];
  __shared__ __align__(16) __bf16 sB[2][4096];
  __shared__ __align__(16) __bf16 sBg[2][4096];
  int t = threadIdx.x, lane = t & 63, wid = t >> 6;
  int wr = wid >> 1, wc = wid & 1, kb4 = lane >> 4, l15 = lane & 15;
  int id = blockIdx.x;
  int id2 = (id & 7) * 160 + (id >> 3);
  int bx = id2 / 20, by = id2 - bx * 20;
  int m0 = bx * 64, n0 = by * 64;
  f32x4 acc_a[2][2] = {}, acc_g[2][2] = {};
  int r0 = t >> 3, c0 = (t & 7) ^ (r0 & 7);

  auto stage = [&](int buf, int k0) {
    gload16(&A[(size_t)(m0 + r0) * 320 + k0 + c0 * 8], &sA[buf][wid * 512]);
    gload16(&A[(size_t)(m0 + 32 + r0) * 320 + k0 + c0 * 8], &sA[buf][2048 + wid * 512]);
    gload16(&Bt[((size_t)(k0 >> 3) + wid) * (2560 * 8) + (size_t)(n0 + lane) * 8], &sB[buf][wid * 512]);
    gload16(&Bt[((size_t)(k0 >> 3) + wid + 4) * (2560 * 8) + (size_t)(n0 + lane) * 8], &sB[buf][2048 + wid * 512]);
    gload16(&Bt[((size_t)(k0 >> 3) + wid) * (2560 * 8) + (size_t)(1280 + n0 + lane) * 8], &sBg[buf][wid * 512]);
    gload16(&Bt[((size_t)(k0 >> 3) + wid + 4) * (2560 * 8) + (size_t)(1280 + n0 + lane) * 8], &sBg[buf][2048 + wid * 512]);
  };
  stage(0, 0);
  __syncthreads();
  int cur = 0;
  for (int k0 = 0; k0 < 320; k0 += 64) {
    if (k0 + 64 < 320) stage(cur ^ 1, k0 + 64);
#pragma unroll
    for (int kk = 0; kk < 2; ++kk) {
      int c8 = kb4 + kk * 4;
      bf16x8 af[2], bfa[2], bfg[2];
#pragma unroll
      for (int fm = 0; fm < 2; ++fm) {
        int row = wr * 32 + fm * 16 + l15;
        af[fm] = *(const bf16x8*)&sA[cur][row * 64 + ((c8 * 8) ^ ((row & 7) << 3))];
      }
#pragma unroll
      for (int fn = 0; fn < 2; ++fn) {
        bfa[fn] = *(const bf16x8*)&sB[cur][(c8 * 64 + wc * 32 + fn * 16 + l15) * 8];
        bfg[fn] = *(const bf16x8*)&sBg[cur][(c8 * 64 + wc * 32 + fn * 16 + l15) * 8];
      }
#pragma unroll
      for (int fm = 0; fm < 2; ++fm)
#pragma unroll
        for (int fn = 0; fn < 2; ++fn) {
          acc_a[fm][fn] = MFMA16(af[fm], bfa[fn], acc_a[fm][fn]);
          acc_g[fm][fn] = MFMA16(af[fm], bfg[fn], acc_g[fm][fn]);
        }
    }
    __syncthreads();
    cur ^= 1;
  }
#pragma unroll
  for (int fm = 0; fm < 2; ++fm)
#pragma unroll
    for (int fn = 0; fn < 2; ++fn)
#pragma unroll
      for (int r = 0; r < 4; ++r) {
        int row = m0 + wr * 32 + fm * 16 + kb4 * 4 + r;
        int col = n0 + wc * 32 + fn * 16 + l15;
        float a = acc_a[fm][fn][r] + bias[col];
        float g = acc_g[fm][fn][r] + bias[1280 + col];
        Out[(size_t)row * 1280 + col] = (__bf16)(a * gelu_exact(g));
      }
}

// ---------------- flash attention: register-direct K/V, dual-q per wave ------
// 512 thr = 4 zz (kv quarters) x 2 kg (key 32-groups). Each wave computes BOTH
// q 32-groups with SHARED K/V fragments. NO barriers / NO LDS in the K-loop.
// No-max softmax; l rides in synthesized ones-row at d=40. 2-phase combine.
__global__ __launch_bounds__(512) void attn_kernel(const __bf16* __restrict__ Qh,
                                                   const __bf16* __restrict__ Kf,
                                                   const __bf16* __restrict__ Vfl,
                                                   const __bf16* __restrict__ Vfh,
                                                   __bf16* __restrict__ Oh,
                                                   int kv_len, int NT) {
  __shared__ float sO[12288];  // [4 slot][2 qg][64 lane][24]
  int t = threadIdx.x, lane = t & 63, wid = t >> 6;
  int zz = wid >> 1, kg = wid & 1;
  int l31 = lane & 31, hi = lane >> 5;
  int id2 = ((blockIdx.x & 7) << 6) | (blockIdx.x >> 3);
  int h = id2 >> 6, q0 = (id2 & 63) * 64;

  bf16x8 qf0[3], qf1[3];
  {
    const __bf16* qr0 = Qh + ((size_t)h * 4096 + q0 + l31) * 48;
    const __bf16* qr1 = Qh + ((size_t)h * 4096 + q0 + 32 + l31) * 48;
#pragma unroll
    for (int s = 0; s < 3; ++s) {
      qf0[s] = *(const bf16x8*)(qr0 + s * 16 + hi * 8);
      qf1[s] = *(const bf16x8*)(qr1 + s * 16 + hi * 8);
    }
  }
  bf16x8 vfill = (l31 == 8) ? ones8() : zero8();  // d=40 ones-row (l accumulator)
  f32x16 oL0 = {}, oH0 = {}, oL1 = {}, oH1 = {};

  int half = (NT >= 4) ? (NT >> 2) : 1;
  int t0 = zz * half; if (t0 > NT) t0 = NT;
  int t1 = t0 + half; if (t1 > NT) t1 = NT;
  for (int tile = t0; tile < t1; ++tile) {
    size_t kb = ((size_t)h * NT + tile) * 2 + kg;
    const __bf16* kp = Kf + kb * 1536 + lane * 8;
    bf16x8 kf0 = *(const bf16x8*)(kp);
    bf16x8 kf1 = *(const bf16x8*)(kp + 512);
    bf16x8 kf2 = *(const bf16x8*)(kp + 1024);
    const __bf16* vp = Vfl + kb * 1024 + lane * 8;
    bf16x8 vl0 = *(const bf16x8*)(vp);
    bf16x8 vl1 = *(const bf16x8*)(vp + 512);
    bf16x8 vh0 = vfill, vh1 = vfill;
    if (l31 < 8) {
      const __bf16* vph = Vfh + kb * 256 + (hi * 8 + l31) * 8;
      vh0 = *(const bf16x8*)(vph);
      vh1 = *(const bf16x8*)(vph + 128);
    }
    // two independent S^T chains sharing K fragments
    f32x16 s0 = {}, s1 = {};
    __builtin_amdgcn_s_setprio(1);
    s0 = MFMA32(kf0, qf0[0], s0);
    s1 = MFMA32(kf0, qf1[0], s1);
    s0 = MFMA32(kf1, qf0[1], s0);
    s1 = MFMA32(kf1, qf1[1], s1);
    s0 = MFMA32(kf2, qf0[2], s0);
    s1 = MFMA32(kf2, qf1[2], s1);
    __builtin_amdgcn_s_setprio(0);
    int k0 = tile << 6;
    if (k0 + 64 > kv_len) {
#pragma unroll
      for (int r = 0; r < 16; ++r) {
        int klo = (r & 3) + 8 * (r >> 2) + 4 * hi;
        if (k0 + kg * 32 + klo >= kv_len) { s0[r] = -1e30f; s1[r] = -1e30f; }
      }
    }
    bf16x8 p00, p01, p10, p11;
#pragma unroll
    for (int j = 0; j < 8; ++j) {
      p00[j] = (__bf16)fexp2(s0[j]);
      p01[j] = (__bf16)fexp2(s0[8 + j]);
      p10[j] = (__bf16)fexp2(s1[j]);
      p11[j] = (__bf16)fexp2(s1[8 + j]);
    }
    __builtin_amdgcn_s_setprio(1);
    oL0 = MFMA32(vl0, p00, oL0);
    oL1 = MFMA32(vl0, p10, oL1);
    oH0 = MFMA32(vh0, p00, oH0);
    oH1 = MFMA32(vh0, p10, oH1);
    oL0 = MFMA32(vl1, p01, oL0);
    oL1 = MFMA32(vl1, p11, oL1);
    oH0 = MFMA32(vh1, p01, oH0);
    oH1 = MFMA32(vh1, p11, oH1);
    __builtin_amdgcn_s_setprio(0);
  }
  // 2-phase in-block combine across the 8 (zz,kg) sources.
  int srcid = zz * 2 + kg;  // 0..7
  auto dumpTo = [&](int slot, const f32x16& ol, const f32x16& oh, int qg) {
    float* dst = sO + (((size_t)slot * 2 + qg) * 64 + lane) * 24;
#pragma unroll
    for (int r = 0; r < 16; ++r) dst[r] = ol[r];
#pragma unroll
    for (int r = 0; r < 4; ++r) dst[16 + r] = oh[r];
    dst[20] = oh[4];
  };
  auto addFrom = [&](int slot, f32x16& ol, f32x16& oh, int qg) {
    const float* sp = sO + (((size_t)slot * 2 + qg) * 64 + lane) * 24;
#pragma unroll
    for (int r = 0; r < 16; ++r) ol[r] += sp[r];
#pragma unroll
    for (int r = 0; r < 4; ++r) oh[r] += sp[16 + r];
    oh[4] += sp[20];
  };
  // phase 1: srcid 4..7 dump; srcid 0..3 absorb their +4 counterpart
  if (srcid >= 4) { dumpTo(srcid - 4, oL0, oH0, 0); dumpTo(srcid - 4, oL1, oH1, 1); }
  __syncthreads();
  if (srcid < 4) { addFrom(srcid, oL0, oH0, 0); addFrom(srcid, oL1, oH1, 1); }
  __syncthreads();
  // phase 2: srcid 1..3 dump; srcid 0 sums + finalizes
  if (srcid >= 1 && srcid < 4) { dumpTo(srcid - 1, oL0, oH0, 0); dumpTo(srcid - 1, oL1, oH1, 1); }
  __syncthreads();
  if (srcid == 0) {
#pragma unroll
    for (int src = 0; src < 3; ++src) { addFrom(src, oL0, oH0, 0); addFrom(src, oL1, oH1, 1); }
#pragma unroll
    for (int qg = 0; qg < 2; ++qg) {
      const f32x16& ol = qg ? oL1 : oL0;
      const f32x16& oh = qg ? oH1 : oH0;
      float ls = __shfl(oh[4], l31);  // l for q at lane l31 (hi=0), reg 4
      float inv = 1.0f / ls;
      __bf16* orow = Oh + ((size_t)h * 4096 + q0 + qg * 32 + l31) * 40;
#pragma unroll
      for (int r = 0; r < 16; r += 2) {
        int d = (r & 3) + 8 * (r >> 2) + 4 * hi;
        bf16x2 o2;
        o2[0] = (__bf16)(ol[r] * inv);
        o2[1] = (__bf16)(ol[r + 1] * inv);
        *(bf16x2*)(orow + d) = o2;
      }
#pragma unroll
      for (int r = 0; r < 4; r += 2) {
        int d = 32 + r + 4 * hi;
        bf16x2 o2;
        o2[0] = (__bf16)(oh[r] * inv);
        o2[1] = (__bf16)(oh[r + 1] * inv);
        *(bf16x2*)(orow + d) = o2;
      }
    }
  }
}

// =============================================================================
extern "C" void kernel_launch(void* const* d_in, const int* in_sizes, int n_in,
                              void* d_out, int out_size, void* d_ws, size_t ws_size,
                              hipStream_t stream) {
  const float* hs    = (const float*)d_in[0];
  const float* ctx   = (const float*)d_in[1];
  const float* gn_g  = (const float*)d_in[2];
  const float* gn_b  = (const float*)d_in[3];
  const float* pi_w  = (const float*)d_in[4];
  const float* pi_b  = (const float*)d_in[5];
  const float* n1_g  = (const float*)d_in[6];
  const float* n1_b  = (const float*)d_in[7];
  const float* a1_q  = (const float*)d_in[8];
  const float* a1_k  = (const float*)d_in[9];
  const float* a1_v  = (const float*)d_in[10];
  const float* a1_o  = (const float*)d_in[11];
  const float* a1_ob = (const float*)d_in[12];
  const float* n2_g  = (const float*)d_in[13];
  const float* n2_b  = (const float*)d_in[14];
  const float* a2_q  = (const float*)d_in[15];
  const float* a2_k  = (const float*)d_in[16];
  const float* a2_v  = (const float*)d_in[17];
  const float* a2_o  = (const float*)d_in[18];
  const float* a2_ob = (const float*)d_in[19];
  const float* n3_g  = (const float*)d_in[20];
  const float* n3_b  = (const float*)d_in[21];
  const float* ff_w1 = (const float*)d_in[22];
  const float* ff_b1 = (const float*)d_in[23];
  const float* ff_w2 = (const float*)d_in[24];
  const float* ff_b2 = (const float*)d_in[25];
  const float* po_w  = (const float*)d_in[26];
  const float* po_b  = (const float*)d_in[27];

  char* p = (char*)d_ws;
  auto alloc = [&](size_t bytes) {
    char* r = p;
    p += (bytes + 255) & ~(size_t)255;
    return r;
  };
  __bf16* wPI  = (__bf16*)alloc((size_t)320 * 320 * 2);
  __bf16* wQKV = (__bf16*)alloc((size_t)320 * 960 * 2);
  __bf16* wO1  = (__bf16*)alloc((size_t)320 * 320 * 2);
  __bf16* wQ2  = (__bf16*)alloc((size_t)320 * 320 * 2);
  __bf16* wKV2 = (__bf16*)alloc((size_t)768 * 640 * 2);
  __bf16* wO2  = (__bf16*)alloc((size_t)320 * 320 * 2);
  __bf16* wFF1 = (__bf16*)alloc((size_t)320 * 2560 * 2);
  __bf16* wFF2 = (__bf16*)alloc((size_t)1280 * 320 * 2);
  __bf16* wPO  = (__bf16*)alloc((size_t)320 * 320 * 2);

  float*  gpart= (float*)alloc((size_t)256 * 2 * 4);
  __bf16* xg   = (__bf16*)alloc((size_t)4096 * 320 * 2);
  float*  h    = (float*)alloc((size_t)4096 * 320 * 4);
  __bf16* hb   = (__bf16*)alloc((size_t)4096 * 320 * 2);
  __bf16* nx   = (__bf16*)alloc((size_t)4096 * 320 * 2);
  __bf16* qh   = (__bf16*)alloc((size_t)8 * 4096 * 48 * 2);
  __bf16* kf   = (__bf16*)alloc((size_t)8 * 64 * 2 * 3 * 512 * 2);
  __bf16* vfl  = (__bf16*)alloc((size_t)8 * 64 * 2 * 2 * 512 * 2);
  __bf16* vfh  = (__bf16*)alloc((size_t)8 * 64 * 2 * 2 * 128 * 2);
  __bf16* kf2  = (__bf16*)alloc((size_t)8 * 2 * 2 * 3 * 512 * 2);
  __bf16* vfl2 = (__bf16*)alloc((size_t)8 * 2 * 2 * 2 * 512 * 2);
  __bf16* vfh2 = (__bf16*)alloc((size_t)8 * 2 * 2 * 2 * 128 * 2);
  __bf16* oh   = (__bf16*)alloc((size_t)4096 * 320 * 2);
  __bf16* g    = (__bf16*)alloc((size_t)4096 * 1280 * 2);
  float*  outp = (float*)d_out;

  // 1. prep: weight convert+transpose (blocks 0..4799) + GN stats (4800..5055)
  WTable tab;
  tab.w[0]  = WDesc{pi_w,  wPI,  320, 320, 320, 0};
  tab.w[1]  = WDesc{a1_q,  wQKV, 320, 320, 960, 0};
  tab.w[2]  = WDesc{a1_k,  wQKV, 320, 320, 960, 320};
  tab.w[3]  = WDesc{a1_v,  wQKV, 320, 320, 960, 640};
  tab.w[4]  = WDesc{a1_o,  wO1,  320, 320, 320, 0};
  tab.w[5]  = WDesc{a2_q,  wQ2,  320, 320, 320, 0};
  tab.w[6]  = WDesc{a2_k,  wKV2, 768, 320, 640, 0};
  tab.w[7]  = WDesc{a2_v,  wKV2, 768, 320, 640, 320};
  tab.w[8]  = WDesc{a2_o,  wO2,  320, 320, 320, 0};
  tab.w[9]  = WDesc{ff_w1, wFF1, 320, 2560, 2560, 0};
  tab.w[10] = WDesc{ff_w2, wFF2, 1280, 320, 320, 0};
  tab.w[11] = WDesc{po_w,  wPO,  320, 320, 320, 0};
  prep_kernel<<<dim3(5056), 256, 0, stream>>>(tab, hs, gpart);
  // 2. groupnorm apply -> xg bf16 [px][c]
  gn_apply<<<dim3(640), 256, 0, stream>>>(hs, gpart, gn_g, gn_b, xg);
  // 3. proj_in
  gemm32<0, true, false, false, false><<<dim3(640), 256, 0, stream>>>(xg, wPI, pi_b, nullptr, h, nullptr, 4096, 320, 320);
  // 4. LN1
  ln_kernel<<<dim3(1024), 256, 0, stream>>>(h, n1_g, n1_b, nx);
  // 5. merged QKV (blocks 0..959) + cross-K/V (960..979)
  qkv_gemm<<<dim3(980), 256, 0, stream>>>(nx, wQKV, qh, kf, vfl, vfh,
                                          ctx, wKV2, kf2, vfl2, vfh2);
  // 6. self attention (register-direct, dual-q waves, 4-way KV split)
  attn_kernel<<<dim3(512), 512, 0, stream>>>(qh, kf, vfl, vfh, oh, 4096, 64);
  // 7. out proj + residual
  gemm32<0, true, true, false, true><<<dim3(640), 256, 0, stream>>>(oh, wO1, a1_ob, h, h, nullptr, 4096, 320, 320);
  // 8. LN2
  ln_kernel<<<dim3(1024), 256, 0, stream>>>(h, n2_g, n2_b, nx);
  // 9. cross q (head-blocked pad-48, scaled)
  gemm32<4, false, false, true, false><<<dim3(640), 256, 0, stream>>>(nx, wQ2, nullptr, nullptr, qh, nullptr, 4096, 320, 320);
  // 10. cross attention (NT=2: zz0 tile0, zz1 tile1 masked, zz2/3 idle-zero)
  attn_kernel<<<dim3(512), 512, 0, stream>>>(qh, kf2, vfl2, vfh2, oh, 77, 2);
  // 11. out proj + residual
  gemm32<0, true, true, false, true><<<dim3(640), 256, 0, stream>>>(oh, wO2, a2_ob, h, h, nullptr, 4096, 320, 320);
  // 12. LN3
  ln_kernel<<<dim3(1024), 256, 0, stream>>>(h, n3_g, n3_b, nx);
  // 13. GEGLU
  geglu64<<<dim3(1280), 256, 0, stream>>>(nx, wFF1, ff_b1, g);
  // 14. FF2 + residual -> h f32 + hb bf16
  gemm32<2, true, true, false, false><<<dim3(640), 256, 0, stream>>>(g, wFF2, ff_b2, h, h, hb, 4096, 320, 1280);
  // 15. proj_out (transposed) + input residual -> d_out
  gemm32<3, true, true, false, false><<<dim3(640), 256, 0, stream>>>(hb, wPO, po_b, hs, outp, nullptr, 4096, 320, 320);
}